// Round 12
// baseline (145.024 us; speedup 1.0000x reference)
//
#include <hip/hip_runtime.h>

// ---------------------------------------------------------------------------
// MoE with adaptive gate, B=8192 D=2048 E=8 H=128, fp32 in/out, bf16 MFMA core
// k_cvt_gate : gate softmax (4 rows/wave, reg-cached gw) + x LDS-transpose
//              convert + W converts, one launch
// k_gemm12f  : fused GEMM1+silu+GEMM2+silu+gate, BM=64 tiles -> 1024 blocks,
//              4 blocks/CU (16 waves/CU) for cross-block latency hiding
// k_gemm3    : out = h2g @ W3flat + gates @ b3 (m97-shape core, 1024 blocks)
// ---------------------------------------------------------------------------

typedef __attribute__((ext_vector_type(8))) short short8;   // 8 bf16 (4 VGPRs)
typedef __attribute__((ext_vector_type(4))) short bf16x4;   // 4 bf16
typedef __attribute__((ext_vector_type(4))) float f32x4;    // MFMA C/D

#define B_SZ 8192
#define D_SZ 2048
#define E_SZ 8
#define H_SZ 128

__device__ __forceinline__ short f2bf(float f) {
  unsigned u = __builtin_bit_cast(unsigned, f);
  unsigned r = (u + 0x7fffu + ((u >> 16) & 1u)) >> 16;   // RNE
  return (short)r;
}

__device__ __forceinline__ float silu_f(float v) {
  return v / (1.f + __expf(-v));
}

__device__ __forceinline__ void gload_lds16(const void* g, void* l) {
  __builtin_amdgcn_global_load_lds(
      (const __attribute__((address_space(1))) void*)g,
      (__attribute__((address_space(3))) void*)l,
      16, 0, 0);
}

// ---------------------------------------------------------------------------
// 128x128 core, BK=32, double-buffered 32 KB LDS.  256 thr, 4 waves (2x2),
// wave-out 64x64, acc[4][4].  Frag-ready global tiles of 8192 shorts:
// elem = kg*1024 + p*8 + j, k = tau*64 + kg*8 + j.   (used by k_gemm3)
// ---------------------------------------------------------------------------
template<int NHT>
__device__ __forceinline__ void core128(const short* __restrict__ A,
                                        const short* __restrict__ B,
                                        short* lds, f32x4 acc[4][4])
{
  const int tid  = threadIdx.x;
  const int lane = tid & 63;
  const int wid  = tid >> 6;
  const int wr = wid >> 1, wc = wid & 1;
  const int lm = lane & 15, lk = lane >> 4;
  const int wl = (tid & ~63) * 8;   // wave-uniform LDS offset (shorts)

  auto STAGE = [&](int eta) {       // 4 x global_load_lds(16B) per thread
    const size_t go = (size_t)(eta >> 1)*8192 + (size_t)(eta & 1)*4096;
    short* l = lds + (eta & 1)*8192;
    gload_lds16(A + go + tid*8,        l + wl);
    gload_lds16(A + go + 2048 + tid*8, l + 2048 + wl);
    gload_lds16(B + go + tid*8,        l + 4096 + wl);
    gload_lds16(B + go + 2048 + tid*8, l + 6144 + wl);
  };

  STAGE(0);
  __syncthreads();
  for (int eta = 0; eta < NHT; ++eta) {
    if (eta + 1 < NHT) STAGE(eta + 1);        // prefetch into other buffer
    const short* la = lds + (eta & 1)*8192 + lk*1024 + (wr*64 + lm)*8;
    const short* lb = lds + (eta & 1)*8192 + 4096 + lk*1024 + (wc*64 + lm)*8;
    short8 av[4], bv[4];
    #pragma unroll
    for (int f = 0; f < 4; ++f) av[f] = *(const short8*)(la + f*128);
    #pragma unroll
    for (int f = 0; f < 4; ++f) bv[f] = *(const short8*)(lb + f*128);
    #pragma unroll
    for (int i = 0; i < 4; ++i)
      #pragma unroll
      for (int j = 0; j < 4; ++j)
        acc[i][j] = __builtin_amdgcn_mfma_f32_16x16x32_bf16(av[i], bv[j], acc[i][j], 0, 0, 0);
    __syncthreads();   // prefetch drained; current-buffer reads complete
  }
}

// ---------------------------------------------------------------------------
// K0: blocks [0,512)     : gate softmax, 16 rows/block (4 rows/wave, fp32)
//     blocks [512,2560)  : xf convert via LDS transpose (coalesced both sides)
//     blocks [2560,4672) : W1/W2/W3 converts (already coalesced)
// ---------------------------------------------------------------------------
__global__ __launch_bounds__(256)
void k_cvt_gate(const float* __restrict__ x,  const float* __restrict__ W1,
                const float* __restrict__ W2, const float* __restrict__ W3,
                const float* __restrict__ gw, const float* __restrict__ gb,
                short* __restrict__ xf, short* __restrict__ w1f,
                short* __restrict__ w2f, short* __restrict__ w3f,
                float* __restrict__ gates)
{
  __shared__ short lt[8192];   // 16 KB (xf branch only)
  const int b = blockIdx.x;
  const int tid = threadIdx.x;

  if (b < 512) {
    // ---- gate: wave handles 4 rows; gw fragments reg-cached, reused ----
    const int lane = tid & 63, wid = tid >> 6;
    const int row0 = b*16 + wid*4;
    float acc[4][8] = {};
    #pragma unroll
    for (int it = 0; it < 8; ++it) {
      const int k = it*256 + lane*4;
      float4 xv[4];
      #pragma unroll
      for (int r = 0; r < 4; ++r)
        xv[r] = *(const float4*)(x + (size_t)(row0 + r)*2048 + k);
      float4 gv[4][2];
      #pragma unroll
      for (int d = 0; d < 4; ++d) {
        gv[d][0] = *(const float4*)(gw + (size_t)(k + d)*8);
        gv[d][1] = *(const float4*)(gw + (size_t)(k + d)*8 + 4);
      }
      #pragma unroll
      for (int r = 0; r < 4; ++r) {
        const float xr[4] = {xv[r].x, xv[r].y, xv[r].z, xv[r].w};
        #pragma unroll
        for (int d = 0; d < 4; ++d) {
          acc[r][0] += xr[d]*gv[d][0].x; acc[r][1] += xr[d]*gv[d][0].y;
          acc[r][2] += xr[d]*gv[d][0].z; acc[r][3] += xr[d]*gv[d][0].w;
          acc[r][4] += xr[d]*gv[d][1].x; acc[r][5] += xr[d]*gv[d][1].y;
          acc[r][6] += xr[d]*gv[d][1].z; acc[r][7] += xr[d]*gv[d][1].w;
        }
      }
    }
    #pragma unroll
    for (int r = 0; r < 4; ++r)
      #pragma unroll
      for (int e = 0; e < 8; ++e)
        #pragma unroll
        for (int d = 1; d < 64; d <<= 1)
          acc[r][e] += __shfl_xor(acc[r][e], d, 64);
    if (lane < 4) {                      // lane r finalizes row0+r
      float lg[8], mx = -1e30f;
      #pragma unroll
      for (int e = 0; e < 8; ++e) { lg[e] = acc[lane][e] + gb[e]; mx = fmaxf(mx, lg[e]); }
      float s = 0.f;
      #pragma unroll
      for (int e = 0; e < 8; ++e) { lg[e] = __expf(lg[e] - mx); s += lg[e]; }
      const float inv = 1.f / s;
      #pragma unroll
      for (int e = 0; e < 8; ++e) gates[(size_t)(row0 + lane)*8 + e] = lg[e] * inv;
    }
  } else if (b < 2560) {
    // ---- xf: tile (bt,kt) = 128 rows x 64 k; coalesced read -> LDS frag ----
    const int t = b - 512;               // tile id (matches xf layout)
    const int bt = t >> 5, kt = t & 31;
    const float* xb = x + (size_t)bt*128*2048 + kt*64;
    #pragma unroll
    for (int u = 0; u < 8; ++u) {
      const int flat = u*1024 + tid*4;   // 0..8191, step 4
      const int row = flat >> 6, kk = flat & 63;
      const float4 v = *(const float4*)(xb + (size_t)row*2048 + kk);
      const int kg = kk >> 3;
      bf16x4 o;
      o[0] = f2bf(v.x); o[1] = f2bf(v.y); o[2] = f2bf(v.z); o[3] = f2bf(v.w);
      // frag idx q = kg*1024 + row*8 + (kk&7); physical = q ^ ((kg&7)<<3)
      const int s = (kg*1024 + row*8 + (kk & 7)) ^ ((kg & 7) << 3);
      *(bf16x4*)(lt + s) = o;
    }
    __syncthreads();
    short* dst = xf + (size_t)t*8192;
    #pragma unroll
    for (int u = 0; u < 4; ++u) {
      const int li = u*2048 + tid*8;
      const int kg = li >> 10;
      const int s = li ^ ((kg & 7) << 3);
      *(short8*)(dst + li) = *(const short8*)(lt + s);
    }
  } else {
    // ---- W converts (coalesced per-j 256B runs) ----
    const int gi = (b - 2560)*256 + tid + 2097152;
    if (gi < 2097152 + 262144) {              // w1f: [e8][kt32] tiles of W1[e]
      const int g = gi - 2097152;
      const int t = g >> 10, r = g & 1023;
      const int e = t >> 5, kt = t & 31;
      const int kg = r >> 7, p = r & 127;
      const int k0 = kt*64 + kg*8;
      short8 o;
      #pragma unroll
      for (int j = 0; j < 8; ++j)
        o[j] = f2bf(W1[(size_t)e*262144 + (size_t)(k0 + j)*128 + p]);
      *(short8*)(w1f + (size_t)g*8) = o;
    } else if (gi < 2097152 + 262144 + 16384) { // w2f: [e8][kt2] tiles of W2[e]
      const int g = gi - (2097152 + 262144);
      const int t = g >> 10, r = g & 1023;
      const int e = t >> 1, kt = t & 1;
      const int kg = r >> 7, p = r & 127;
      const int k0 = kt*64 + kg*8;
      short8 o;
      #pragma unroll
      for (int j = 0; j < 8; ++j)
        o[j] = f2bf(W2[(size_t)e*16384 + (size_t)(k0 + j)*128 + p]);
      *(short8*)(w2f + (size_t)g*8) = o;
    } else if (gi < 2637824) {                // w3f: [nt16][kt16] tiles of W3flat
      const int g = gi - 2375680;
      const int t = g >> 10, r = g & 1023;
      const int nt = t >> 4, kt = t & 15;
      const int kg = r >> 7, p = r & 127;
      const int k0 = kt*64 + kg*8;
      short8 o;
      #pragma unroll
      for (int j = 0; j < 8; ++j) {
        const int k = k0 + j;                 // k = e*128 + h
        o[j] = f2bf(W3[(size_t)(k >> 7)*262144 + (size_t)(k & 127)*2048 + nt*128 + p]);
      }
      *(short8*)(w3f + (size_t)g*8) = o;
    }
  }
}

// ---------------------------------------------------------------------------
// K2: fused GEMM1+silu+GEMM2+silu+gate -> h2gf frag tiles.  BM=64, BN=128.
// grid 1024: e = b&7 (== XCD, W1[e]/W2[e] L2-resident), bt2 = b>>3 (0..127,
// rows [bt2*64, bt2*64+64)).  256 thr, 4 waves (2Mx2N), wave-out 32x64,
// acc[2][4].  LDS 24 KB = 2 buf x (A 4KB | B 8KB).  K=2048 -> 64 half-tiles.
// ---------------------------------------------------------------------------
__global__ __launch_bounds__(256, 4)
void k_gemm12f(const short* __restrict__ xf, const short* __restrict__ w1f,
               const short* __restrict__ w2f,
               const float* __restrict__ b1, const float* __restrict__ b2,
               const float* __restrict__ gates, short* __restrict__ h2gf)
{
  __shared__ short lds[12288];   // 24 KB
  const int b = blockIdx.x;
  const int e   = b & 7;
  const int bt2 = b >> 3;

  const int tid = threadIdx.x, lane = tid & 63, wid = tid >> 6;
  const int wm = wid >> 1, wn = wid & 1;    // wave-out 32x64
  const int lm = lane & 15, lk = lane >> 4, lr = lane >> 4;
  const int lane8 = lane * 8;
  const int w3c = wid * 3;                  // 3 staging units per wave

  // A: rows (bt2&1)*64 of xf tile (bt2>>1, tau); chunk u = kg-in-half (1 KB)
  const short* Ax = xf  + (size_t)(bt2 >> 1)*32*8192 + (bt2 & 1)*512;
  const short* Bw = w1f + (size_t)e*32*8192;

  auto STAGE = [&](int eta) {   // 12 x 1KB units; 3 gload_lds16 per thread
    const size_t go = (size_t)(eta >> 1)*8192 + (size_t)(eta & 1)*4096;
    short* l = lds + (eta & 1)*6144;
    #pragma unroll
    for (int c = 0; c < 3; ++c) {
      const int u = w3c + c;                // wave-uniform
      if (u < 4)
        gload_lds16(Ax + go + u*1024 + lane8, l + u*512);
      else
        gload_lds16(Bw + go + (u - 4)*512 + lane8, l + 2048 + (u - 4)*512);
    }
  };

  f32x4 acc[2][4] = {};
  STAGE(0);
  __syncthreads();
  for (int eta = 0; eta < 64; ++eta) {
    if (eta + 1 < 64) STAGE(eta + 1);
    const short* la = lds + (eta & 1)*6144 + lk*512 + (wm*32 + lm)*8;
    const short* lb = lds + (eta & 1)*6144 + 2048 + lk*1024 + (wn*64 + lm)*8;
    short8 av[2], bv[4];
    #pragma unroll
    for (int f = 0; f < 2; ++f) av[f] = *(const short8*)(la + f*128);
    #pragma unroll
    for (int f = 0; f < 4; ++f) bv[f] = *(const short8*)(lb + f*128);
    #pragma unroll
    for (int i = 0; i < 2; ++i)
      #pragma unroll
      for (int j = 0; j < 4; ++j)
        acc[i][j] = __builtin_amdgcn_mfma_f32_16x16x32_bf16(av[i], bv[j], acc[i][j], 0, 0, 0);
    __syncthreads();
  }

  // ---- W2 fragments direct global->VGPR (L2-resident) ----
  short8 bvAll[2][2][4];
  #pragma unroll
  for (int kt = 0; kt < 2; ++kt)
  #pragma unroll
  for (int ks = 0; ks < 2; ++ks)
  #pragma unroll
  for (int fn = 0; fn < 4; ++fn)
    bvAll[kt][ks][fn] = *(const short8*)(
        w2f + (size_t)e*16384 + kt*8192 + (ks*4 + lk)*1024
            + (wn*64 + fn*16 + lm)*8);

  // ---- gates for my 8 output rows ----
  float gv[2][4];
  #pragma unroll
  for (int fm = 0; fm < 2; ++fm)
  #pragma unroll
  for (int i = 0; i < 4; ++i)
    gv[fm][i] = gates[(size_t)(bt2*64 + wm*32 + fm*16 + lr*4 + i)*8 + e];

  // ---- h1 = silu(acc + b1) -> LDS frag [kg16][p64][j8] (16 KB) ----
  float b1v[4];
  #pragma unroll
  for (int fn = 0; fn < 4; ++fn) b1v[fn] = b1[e*H_SZ + wn*64 + fn*16 + lm];
  #pragma unroll
  for (int fm = 0; fm < 2; ++fm)
  #pragma unroll
  for (int i = 0; i < 4; ++i) {
    const int m = wm*32 + fm*16 + lr*4 + i;        // 0..63
    #pragma unroll
    for (int fn = 0; fn < 4; ++fn) {
      const int n = wn*64 + fn*16 + lm;            // h index 0..127
      const float v = silu_f(acc[fm][fn][i] + b1v[fn]);
      lds[(n >> 3)*512 + m*8 + (n & 7)] = f2bf(v);
    }
  }
  __syncthreads();

  // ---- GEMM2: h2 = h1 @ W2[e], K=128 ----
  f32x4 acc2[2][4] = {};
  #pragma unroll
  for (int kt = 0; kt < 2; ++kt)
  #pragma unroll
  for (int ks = 0; ks < 2; ++ks) {
    short8 av2[2];
    #pragma unroll
    for (int f = 0; f < 2; ++f)
      av2[f] = *(const short8*)(lds + (kt*8 + ks*4 + lk)*512 + (wm*32 + f*16 + lm)*8);
    #pragma unroll
    for (int i = 0; i < 2; ++i)
      #pragma unroll
      for (int j = 0; j < 4; ++j)
        acc2[i][j] = __builtin_amdgcn_mfma_f32_16x16x32_bf16(
            av2[i], bvAll[kt][ks][j], acc2[i][j], 0, 0, 0);
  }
  __syncthreads();   // all h1 reads done; reuse LDS for h2

  // ---- h2 = silu(acc2 + b2) * gate -> LDS frag ----
  float b2v[4];
  #pragma unroll
  for (int fn = 0; fn < 4; ++fn) b2v[fn] = b2[e*H_SZ + wn*64 + fn*16 + lm];
  #pragma unroll
  for (int fm = 0; fm < 2; ++fm)
  #pragma unroll
  for (int i = 0; i < 4; ++i) {
    const int m = wm*32 + fm*16 + lr*4 + i;
    const float g = gv[fm][i];
    #pragma unroll
    for (int fn = 0; fn < 4; ++fn) {
      const int n = wn*64 + fn*16 + lm;
      const float v = silu_f(acc2[fm][fn][i] + b2v[fn]) * g;
      lds[(n >> 3)*512 + m*8 + (n & 7)] = f2bf(v);
    }
  }
  __syncthreads();

  // ---- dump h2 (8192 shorts) -> h2gf tiles (bt*16 + e*2 + t2) ----
  const size_t tb = ((size_t)(bt2 >> 1)*16 + e*2)*8192 + (size_t)(bt2 & 1)*512;
  #pragma unroll
  for (int u = 0; u < 4; ++u) {
    const int li = u*2048 + tid*8;                 // 0..8191
    const int kg = li >> 9;                        // 0..15
    const int p  = (li >> 3) & 63;
    short* dst = h2gf + tb + (size_t)(kg >> 3)*8192 + (kg & 7)*1024 + p*8;
    *(short8*)dst = *(const short8*)(lds + li);
  }
}

// ---------------------------------------------------------------------------
// K4: out = h2g @ W3flat + gates @ b3.  1024 blocks XCD-chunked.
// ---------------------------------------------------------------------------
__global__ __launch_bounds__(256, 4)
void k_gemm3(const short* __restrict__ h2gf, const short* __restrict__ w3f,
             const float* __restrict__ b3, const float* __restrict__ gates,
             float* __restrict__ out)
{
  __shared__ short lds[16384];   // 32 KB
  const int b = blockIdx.x;
  const int xcd = b & 7, idx = b >> 3;   // idx 0..127
  const int bt = xcd*8 + (idx & 7);      // 0..63
  const int nt = idx >> 3;               // 0..15

  f32x4 acc[4][4] = {};
  core128<32>(h2gf + (size_t)bt*16*8192,
              w3f  + (size_t)nt*16*8192,
              lds, acc);

  const int tid = threadIdx.x, lane = tid & 63, wid = tid >> 6;
  const int wr = wid >> 1, wc = wid & 1, lm = lane & 15, lr = lane >> 4;
  float b3c[4][8];
  #pragma unroll
  for (int fn = 0; fn < 4; ++fn) {
    const int n = nt*128 + wc*64 + fn*16 + lm;
    #pragma unroll
    for (int e = 0; e < 8; ++e) b3c[fn][e] = b3[(size_t)e*D_SZ + n];
  }
  #pragma unroll
  for (int fm = 0; fm < 4; ++fm)
  #pragma unroll
  for (int i = 0; i < 4; ++i) {
    const int m = bt*128 + wr*64 + fm*16 + lr*4 + i;
    const float4 ga  = *(const float4*)(gates + (size_t)m*8);
    const float4 gbv = *(const float4*)(gates + (size_t)m*8 + 4);
    #pragma unroll
    for (int fn = 0; fn < 4; ++fn) {
      const int n = nt*128 + wc*64 + fn*16 + lm;
      const float bias = ga.x*b3c[fn][0] + ga.y*b3c[fn][1] + ga.z*b3c[fn][2] + ga.w*b3c[fn][3]
                       + gbv.x*b3c[fn][4] + gbv.y*b3c[fn][5] + gbv.z*b3c[fn][6] + gbv.w*b3c[fn][7];
      out[(size_t)m*D_SZ + n] = acc[fm][fn][i] + bias;
    }
  }
}

// ---------------------------------------------------------------------------
extern "C" void kernel_launch(void* const* d_in, const int* in_sizes, int n_in,
                              void* d_out, int out_size, void* d_ws, size_t ws_size,
                              hipStream_t stream)
{
  (void)in_sizes; (void)n_in; (void)out_size; (void)ws_size;
  const float* x  = (const float*)d_in[0];
  const float* gw = (const float*)d_in[1];
  const float* gb = (const float*)d_in[2];
  const float* W1 = (const float*)d_in[3];
  const float* b1 = (const float*)d_in[4];
  const float* W2 = (const float*)d_in[5];
  const float* b2 = (const float*)d_in[6];
  const float* W3 = (const float*)d_in[7];
  const float* b3 = (const float*)d_in[8];
  float* out = (float*)d_out;

  char* ws = (char*)d_ws;
  short* xf    = (short*)ws;  ws += (size_t)B_SZ*D_SZ*2;          // 33.5 MB
  short* w1f   = (short*)ws;  ws += (size_t)E_SZ*D_SZ*H_SZ*2;     //  4.2 MB
  short* w2f   = (short*)ws;  ws += (size_t)E_SZ*H_SZ*H_SZ*2;     //  0.26 MB
  short* w3f   = (short*)ws;  ws += (size_t)E_SZ*H_SZ*D_SZ*2;     //  4.2 MB
  float* gates = (float*)ws;  ws += (size_t)B_SZ*E_SZ*4;          //  0.26 MB
  short* h2gf  = (short*)ws;  ws += (size_t)B_SZ*E_SZ*H_SZ*2;     // 16.8 MB

  k_cvt_gate<<<dim3(4672), dim3(256), 0, stream>>>(x, W1, W2, W3, gw, gb,
                                                   xf, w1f, w2f, w3f, gates);
  k_gemm12f <<<dim3(1024), dim3(256), 0, stream>>>(xf, w1f, w2f, b1, b2, gates, h2gf);
  k_gemm3   <<<dim3(1024), dim3(256), 0, stream>>>(h2gf, w3f, b3, gates, out);
}

// Round 13
// 141.558 us; speedup vs baseline: 1.0245x; 1.0245x over previous
//
#include <hip/hip_runtime.h>

// ---------------------------------------------------------------------------
// MoE with adaptive gate, B=8192 D=2048 E=8 H=128, fp32 in/out, bf16 MFMA core
// k_cvt_gate : gate softmax + x LDS-transpose convert + W converts
// k_gemm12f  : fused GEMM1+silu+GEMM2+silu+gate, BM=64 -> 1024 blocks,
//              4 blocks/CU; XCD-local A slices (bt2 = xcd*16+.., e outer)
// k_gemm3    : out = h2g @ W3flat + gates @ b3 (m97-shape core, 1024 blocks)
// ---------------------------------------------------------------------------

typedef __attribute__((ext_vector_type(8))) short short8;   // 8 bf16 (4 VGPRs)
typedef __attribute__((ext_vector_type(4))) short bf16x4;   // 4 bf16
typedef __attribute__((ext_vector_type(4))) float f32x4;    // MFMA C/D

#define B_SZ 8192
#define D_SZ 2048
#define E_SZ 8
#define H_SZ 128

__device__ __forceinline__ short f2bf(float f) {
  unsigned u = __builtin_bit_cast(unsigned, f);
  unsigned r = (u + 0x7fffu + ((u >> 16) & 1u)) >> 16;   // RNE
  return (short)r;
}

__device__ __forceinline__ float silu_f(float v) {
  return v / (1.f + __expf(-v));
}

__device__ __forceinline__ void gload_lds16(const void* g, void* l) {
  __builtin_amdgcn_global_load_lds(
      (const __attribute__((address_space(1))) void*)g,
      (__attribute__((address_space(3))) void*)l,
      16, 0, 0);
}

// ---------------------------------------------------------------------------
// 128x128 core, BK=32, double-buffered 32 KB LDS.  256 thr, 4 waves (2x2),
// wave-out 64x64, acc[4][4].  Frag-ready global tiles of 8192 shorts:
// elem = kg*1024 + p*8 + j, k = tau*64 + kg*8 + j.   (used by k_gemm3)
// ---------------------------------------------------------------------------
template<int NHT>
__device__ __forceinline__ void core128(const short* __restrict__ A,
                                        const short* __restrict__ B,
                                        short* lds, f32x4 acc[4][4])
{
  const int tid  = threadIdx.x;
  const int lane = tid & 63;
  const int wid  = tid >> 6;
  const int wr = wid >> 1, wc = wid & 1;
  const int lm = lane & 15, lk = lane >> 4;
  const int wl = (tid & ~63) * 8;   // wave-uniform LDS offset (shorts)

  auto STAGE = [&](int eta) {       // 4 x global_load_lds(16B) per thread
    const size_t go = (size_t)(eta >> 1)*8192 + (size_t)(eta & 1)*4096;
    short* l = lds + (eta & 1)*8192;
    gload_lds16(A + go + tid*8,        l + wl);
    gload_lds16(A + go + 2048 + tid*8, l + 2048 + wl);
    gload_lds16(B + go + tid*8,        l + 4096 + wl);
    gload_lds16(B + go + 2048 + tid*8, l + 6144 + wl);
  };

  STAGE(0);
  __syncthreads();
  for (int eta = 0; eta < NHT; ++eta) {
    if (eta + 1 < NHT) STAGE(eta + 1);        // prefetch into other buffer
    const short* la = lds + (eta & 1)*8192 + lk*1024 + (wr*64 + lm)*8;
    const short* lb = lds + (eta & 1)*8192 + 4096 + lk*1024 + (wc*64 + lm)*8;
    short8 av[4], bv[4];
    #pragma unroll
    for (int f = 0; f < 4; ++f) av[f] = *(const short8*)(la + f*128);
    #pragma unroll
    for (int f = 0; f < 4; ++f) bv[f] = *(const short8*)(lb + f*128);
    #pragma unroll
    for (int i = 0; i < 4; ++i)
      #pragma unroll
      for (int j = 0; j < 4; ++j)
        acc[i][j] = __builtin_amdgcn_mfma_f32_16x16x32_bf16(av[i], bv[j], acc[i][j], 0, 0, 0);
    __syncthreads();   // prefetch drained; current-buffer reads complete
  }
}

// ---------------------------------------------------------------------------
// K0: blocks [0,512)     : gate softmax, 16 rows/block (4 rows/wave, fp32)
//     blocks [512,2560)  : xf convert via LDS transpose (coalesced both sides)
//     blocks [2560,4672) : W1/W2/W3 converts (already coalesced)
// ---------------------------------------------------------------------------
__global__ __launch_bounds__(256)
void k_cvt_gate(const float* __restrict__ x,  const float* __restrict__ W1,
                const float* __restrict__ W2, const float* __restrict__ W3,
                const float* __restrict__ gw, const float* __restrict__ gb,
                short* __restrict__ xf, short* __restrict__ w1f,
                short* __restrict__ w2f, short* __restrict__ w3f,
                float* __restrict__ gates)
{
  __shared__ short lt[8192];   // 16 KB (xf branch only)
  const int b = blockIdx.x;
  const int tid = threadIdx.x;

  if (b < 512) {
    // ---- gate: wave handles 4 rows; gw fragments reg-cached, reused ----
    const int lane = tid & 63, wid = tid >> 6;
    const int row0 = b*16 + wid*4;
    float acc[4][8] = {};
    #pragma unroll
    for (int it = 0; it < 8; ++it) {
      const int k = it*256 + lane*4;
      float4 xv[4];
      #pragma unroll
      for (int r = 0; r < 4; ++r)
        xv[r] = *(const float4*)(x + (size_t)(row0 + r)*2048 + k);
      float4 gv[4][2];
      #pragma unroll
      for (int d = 0; d < 4; ++d) {
        gv[d][0] = *(const float4*)(gw + (size_t)(k + d)*8);
        gv[d][1] = *(const float4*)(gw + (size_t)(k + d)*8 + 4);
      }
      #pragma unroll
      for (int r = 0; r < 4; ++r) {
        const float xr[4] = {xv[r].x, xv[r].y, xv[r].z, xv[r].w};
        #pragma unroll
        for (int d = 0; d < 4; ++d) {
          acc[r][0] += xr[d]*gv[d][0].x; acc[r][1] += xr[d]*gv[d][0].y;
          acc[r][2] += xr[d]*gv[d][0].z; acc[r][3] += xr[d]*gv[d][0].w;
          acc[r][4] += xr[d]*gv[d][1].x; acc[r][5] += xr[d]*gv[d][1].y;
          acc[r][6] += xr[d]*gv[d][1].z; acc[r][7] += xr[d]*gv[d][1].w;
        }
      }
    }
    #pragma unroll
    for (int r = 0; r < 4; ++r)
      #pragma unroll
      for (int e = 0; e < 8; ++e)
        #pragma unroll
        for (int d = 1; d < 64; d <<= 1)
          acc[r][e] += __shfl_xor(acc[r][e], d, 64);
    if (lane < 4) {                      // lane r finalizes row0+r
      float lg[8], mx = -1e30f;
      #pragma unroll
      for (int e = 0; e < 8; ++e) { lg[e] = acc[lane][e] + gb[e]; mx = fmaxf(mx, lg[e]); }
      float s = 0.f;
      #pragma unroll
      for (int e = 0; e < 8; ++e) { lg[e] = __expf(lg[e] - mx); s += lg[e]; }
      const float inv = 1.f / s;
      #pragma unroll
      for (int e = 0; e < 8; ++e) gates[(size_t)(row0 + lane)*8 + e] = lg[e] * inv;
    }
  } else if (b < 2560) {
    // ---- xf: tile (bt,kt) = 128 rows x 64 k; coalesced read -> LDS frag ----
    const int t = b - 512;               // tile id (matches xf layout)
    const int bt = t >> 5, kt = t & 31;
    const float* xb = x + (size_t)bt*128*2048 + kt*64;
    #pragma unroll
    for (int u = 0; u < 8; ++u) {
      const int flat = u*1024 + tid*4;   // 0..8191, step 4
      const int row = flat >> 6, kk = flat & 63;
      const float4 v = *(const float4*)(xb + (size_t)row*2048 + kk);
      const int kg = kk >> 3;
      bf16x4 o;
      o[0] = f2bf(v.x); o[1] = f2bf(v.y); o[2] = f2bf(v.z); o[3] = f2bf(v.w);
      // frag idx q = kg*1024 + row*8 + (kk&7); physical = q ^ ((kg&7)<<3)
      const int s = (kg*1024 + row*8 + (kk & 7)) ^ ((kg & 7) << 3);
      *(bf16x4*)(lt + s) = o;
    }
    __syncthreads();
    short* dst = xf + (size_t)t*8192;
    #pragma unroll
    for (int u = 0; u < 4; ++u) {
      const int li = u*2048 + tid*8;
      const int kg = li >> 10;
      const int s = li ^ ((kg & 7) << 3);
      *(short8*)(dst + li) = *(const short8*)(lt + s);
    }
  } else {
    // ---- W converts (coalesced per-j 256B runs) ----
    const int gi = (b - 2560)*256 + tid + 2097152;
    if (gi < 2097152 + 262144) {              // w1f: [e8][kt32] tiles of W1[e]
      const int g = gi - 2097152;
      const int t = g >> 10, r = g & 1023;
      const int e = t >> 5, kt = t & 31;
      const int kg = r >> 7, p = r & 127;
      const int k0 = kt*64 + kg*8;
      short8 o;
      #pragma unroll
      for (int j = 0; j < 8; ++j)
        o[j] = f2bf(W1[(size_t)e*262144 + (size_t)(k0 + j)*128 + p]);
      *(short8*)(w1f + (size_t)g*8) = o;
    } else if (gi < 2097152 + 262144 + 16384) { // w2f: [e8][kt2] tiles of W2[e]
      const int g = gi - (2097152 + 262144);
      const int t = g >> 10, r = g & 1023;
      const int e = t >> 1, kt = t & 1;
      const int kg = r >> 7, p = r & 127;
      const int k0 = kt*64 + kg*8;
      short8 o;
      #pragma unroll
      for (int j = 0; j < 8; ++j)
        o[j] = f2bf(W2[(size_t)e*16384 + (size_t)(k0 + j)*128 + p]);
      *(short8*)(w2f + (size_t)g*8) = o;
    } else if (gi < 2637824) {                // w3f: [nt16][kt16] tiles of W3flat
      const int g = gi - 2375680;
      const int t = g >> 10, r = g & 1023;
      const int nt = t >> 4, kt = t & 15;
      const int kg = r >> 7, p = r & 127;
      const int k0 = kt*64 + kg*8;
      short8 o;
      #pragma unroll
      for (int j = 0; j < 8; ++j) {
        const int k = k0 + j;                 // k = e*128 + h
        o[j] = f2bf(W3[(size_t)(k >> 7)*262144 + (size_t)(k & 127)*2048 + nt*128 + p]);
      }
      *(short8*)(w3f + (size_t)g*8) = o;
    }
  }
}

// ---------------------------------------------------------------------------
// K2: fused GEMM1+silu+GEMM2+silu+gate -> h2gf frag tiles.  BM=64, BN=128.
// grid 1024 XCD-local: xcd = b&7, idx = b>>3 (0..127);
//   bt2 = xcd*16 + (idx & 15)  (XCD owns a contiguous 4.2 MB xf slice, L2-hot)
//   e   = idx >> 4             (expert varies slowly -> W1[e]/W2[e] L2-hot)
// 256 thr, 4 waves (2Mx2N), wave-out 32x64, acc[2][4].
// LDS 24 KB = 2 buf x (A 4KB | B 8KB).  K=2048 -> 64 half-tiles.
// ---------------------------------------------------------------------------
__global__ __launch_bounds__(256, 4)
void k_gemm12f(const short* __restrict__ xf, const short* __restrict__ w1f,
               const short* __restrict__ w2f,
               const float* __restrict__ b1, const float* __restrict__ b2,
               const float* __restrict__ gates, short* __restrict__ h2gf)
{
  __shared__ short lds[12288];   // 24 KB
  const int b = blockIdx.x;
  const int xcd = b & 7, idx = b >> 3;      // idx 0..127
  const int bt2 = xcd*16 + (idx & 15);      // 0..127  (rows [bt2*64, +64))
  const int e   = idx >> 4;                 // 0..7

  const int tid = threadIdx.x, lane = tid & 63, wid = tid >> 6;
  const int wm = wid >> 1, wn = wid & 1;    // wave-out 32x64
  const int lm = lane & 15, lk = lane >> 4, lr = lane >> 4;
  const int lane8 = lane * 8;
  const int w3c = wid * 3;                  // 3 staging units per wave

  // A: rows (bt2&1)*64 of xf tile (bt2>>1, tau); chunk u = kg-in-half (1 KB)
  const short* Ax = xf  + (size_t)(bt2 >> 1)*32*8192 + (bt2 & 1)*512;
  const short* Bw = w1f + (size_t)e*32*8192;

  auto STAGE = [&](int eta) {   // 12 x 1KB units; 3 gload_lds16 per thread
    const size_t go = (size_t)(eta >> 1)*8192 + (size_t)(eta & 1)*4096;
    short* l = lds + (eta & 1)*6144;
    #pragma unroll
    for (int c = 0; c < 3; ++c) {
      const int u = w3c + c;                // wave-uniform
      if (u < 4)
        gload_lds16(Ax + go + u*1024 + lane8, l + u*512);
      else
        gload_lds16(Bw + go + (u - 4)*512 + lane8, l + 2048 + (u - 4)*512);
    }
  };

  f32x4 acc[2][4] = {};
  STAGE(0);
  __syncthreads();
  for (int eta = 0; eta < 64; ++eta) {
    if (eta + 1 < 64) STAGE(eta + 1);
    const short* la = lds + (eta & 1)*6144 + lk*512 + (wm*32 + lm)*8;
    const short* lb = lds + (eta & 1)*6144 + 2048 + lk*1024 + (wn*64 + lm)*8;
    short8 av[2], bv[4];
    #pragma unroll
    for (int f = 0; f < 2; ++f) av[f] = *(const short8*)(la + f*128);
    #pragma unroll
    for (int f = 0; f < 4; ++f) bv[f] = *(const short8*)(lb + f*128);
    #pragma unroll
    for (int i = 0; i < 2; ++i)
      #pragma unroll
      for (int j = 0; j < 4; ++j)
        acc[i][j] = __builtin_amdgcn_mfma_f32_16x16x32_bf16(av[i], bv[j], acc[i][j], 0, 0, 0);
    __syncthreads();
  }

  // ---- W2 fragments direct global->VGPR (L2-resident) ----
  short8 bvAll[2][2][4];
  #pragma unroll
  for (int kt = 0; kt < 2; ++kt)
  #pragma unroll
  for (int ks = 0; ks < 2; ++ks)
  #pragma unroll
  for (int fn = 0; fn < 4; ++fn)
    bvAll[kt][ks][fn] = *(const short8*)(
        w2f + (size_t)e*16384 + kt*8192 + (ks*4 + lk)*1024
            + (wn*64 + fn*16 + lm)*8);

  // ---- gates for my 8 output rows ----
  float gv[2][4];
  #pragma unroll
  for (int fm = 0; fm < 2; ++fm)
  #pragma unroll
  for (int i = 0; i < 4; ++i)
    gv[fm][i] = gates[(size_t)(bt2*64 + wm*32 + fm*16 + lr*4 + i)*8 + e];

  // ---- h1 = silu(acc + b1) -> LDS frag [kg16][p64][j8] (16 KB) ----
  float b1v[4];
  #pragma unroll
  for (int fn = 0; fn < 4; ++fn) b1v[fn] = b1[e*H_SZ + wn*64 + fn*16 + lm];
  #pragma unroll
  for (int fm = 0; fm < 2; ++fm)
  #pragma unroll
  for (int i = 0; i < 4; ++i) {
    const int m = wm*32 + fm*16 + lr*4 + i;        // 0..63
    #pragma unroll
    for (int fn = 0; fn < 4; ++fn) {
      const int n = wn*64 + fn*16 + lm;            // h index 0..127
      const float v = silu_f(acc[fm][fn][i] + b1v[fn]);
      lds[(n >> 3)*512 + m*8 + (n & 7)] = f2bf(v);
    }
  }
  __syncthreads();

  // ---- GEMM2: h2 = h1 @ W2[e], K=128 ----
  f32x4 acc2[2][4] = {};
  #pragma unroll
  for (int kt = 0; kt < 2; ++kt)
  #pragma unroll
  for (int ks = 0; ks < 2; ++ks) {
    short8 av2[2];
    #pragma unroll
    for (int f = 0; f < 2; ++f)
      av2[f] = *(const short8*)(lds + (kt*8 + ks*4 + lk)*512 + (wm*32 + f*16 + lm)*8);
    #pragma unroll
    for (int i = 0; i < 2; ++i)
      #pragma unroll
      for (int j = 0; j < 4; ++j)
        acc2[i][j] = __builtin_amdgcn_mfma_f32_16x16x32_bf16(
            av2[i], bvAll[kt][ks][j], acc2[i][j], 0, 0, 0);
  }
  __syncthreads();   // all h1 reads done; reuse LDS for h2

  // ---- h2 = silu(acc2 + b2) * gate -> LDS frag ----
  float b2v[4];
  #pragma unroll
  for (int fn = 0; fn < 4; ++fn) b2v[fn] = b2[e*H_SZ + wn*64 + fn*16 + lm];
  #pragma unroll
  for (int fm = 0; fm < 2; ++fm)
  #pragma unroll
  for (int i = 0; i < 4; ++i) {
    const int m = wm*32 + fm*16 + lr*4 + i;
    const float g = gv[fm][i];
    #pragma unroll
    for (int fn = 0; fn < 4; ++fn) {
      const int n = wn*64 + fn*16 + lm;
      const float v = silu_f(acc2[fm][fn][i] + b2v[fn]) * g;
      lds[(n >> 3)*512 + m*8 + (n & 7)] = f2bf(v);
    }
  }
  __syncthreads();

  // ---- dump h2 (8192 shorts) -> h2gf tiles (bt*16 + e*2 + t2) ----
  const size_t tb = ((size_t)(bt2 >> 1)*16 + e*2)*8192 + (size_t)(bt2 & 1)*512;
  #pragma unroll
  for (int u = 0; u < 4; ++u) {
    const int li = u*2048 + tid*8;                 // 0..8191
    const int kg = li >> 9;                        // 0..15
    const int p  = (li >> 3) & 63;
    short* dst = h2gf + tb + (size_t)(kg >> 3)*8192 + (kg & 7)*1024 + p*8;
    *(short8*)dst = *(const short8*)(lds + li);
  }
}

// ---------------------------------------------------------------------------
// K4: out = h2g @ W3flat + gates @ b3.  1024 blocks XCD-chunked.
// ---------------------------------------------------------------------------
__global__ __launch_bounds__(256, 4)
void k_gemm3(const short* __restrict__ h2gf, const short* __restrict__ w3f,
             const float* __restrict__ b3, const float* __restrict__ gates,
             float* __restrict__ out)
{
  __shared__ short lds[16384];   // 32 KB
  const int b = blockIdx.x;
  const int xcd = b & 7, idx = b >> 3;   // idx 0..127
  const int bt = xcd*8 + (idx & 7);      // 0..63
  const int nt = idx >> 3;               // 0..15

  f32x4 acc[4][4] = {};
  core128<32>(h2gf + (size_t)bt*16*8192,
              w3f  + (size_t)nt*16*8192,
              lds, acc);

  const int tid = threadIdx.x, lane = tid & 63, wid = tid >> 6;
  const int wr = wid >> 1, wc = wid & 1, lm = lane & 15, lr = lane >> 4;
  float b3c[4][8];
  #pragma unroll
  for (int fn = 0; fn < 4; ++fn) {
    const int n = nt*128 + wc*64 + fn*16 + lm;
    #pragma unroll
    for (int e = 0; e < 8; ++e) b3c[fn][e] = b3[(size_t)e*D_SZ + n];
  }
  #pragma unroll
  for (int fm = 0; fm < 4; ++fm)
  #pragma unroll
  for (int i = 0; i < 4; ++i) {
    const int m = bt*128 + wr*64 + fm*16 + lr*4 + i;
    const float4 ga  = *(const float4*)(gates + (size_t)m*8);
    const float4 gbv = *(const float4*)(gates + (size_t)m*8 + 4);
    #pragma unroll
    for (int fn = 0; fn < 4; ++fn) {
      const int n = nt*128 + wc*64 + fn*16 + lm;
      const float bias = ga.x*b3c[fn][0] + ga.y*b3c[fn][1] + ga.z*b3c[fn][2] + ga.w*b3c[fn][3]
                       + gbv.x*b3c[fn][4] + gbv.y*b3c[fn][5] + gbv.z*b3c[fn][6] + gbv.w*b3c[fn][7];
      out[(size_t)m*D_SZ + n] = acc[fm][fn][i] + bias;
    }
  }
}

// ---------------------------------------------------------------------------
extern "C" void kernel_launch(void* const* d_in, const int* in_sizes, int n_in,
                              void* d_out, int out_size, void* d_ws, size_t ws_size,
                              hipStream_t stream)
{
  (void)in_sizes; (void)n_in; (void)out_size; (void)ws_size;
  const float* x  = (const float*)d_in[0];
  const float* gw = (const float*)d_in[1];
  const float* gb = (const float*)d_in[2];
  const float* W1 = (const float*)d_in[3];
  const float* b1 = (const float*)d_in[4];
  const float* W2 = (const float*)d_in[5];
  const float* b2 = (const float*)d_in[6];
  const float* W3 = (const float*)d_in[7];
  const float* b3 = (const float*)d_in[8];
  float* out = (float*)d_out;

  char* ws = (char*)d_ws;
  short* xf    = (short*)ws;  ws += (size_t)B_SZ*D_SZ*2;          // 33.5 MB
  short* w1f   = (short*)ws;  ws += (size_t)E_SZ*D_SZ*H_SZ*2;     //  4.2 MB
  short* w2f   = (short*)ws;  ws += (size_t)E_SZ*H_SZ*H_SZ*2;     //  0.26 MB
  short* w3f   = (short*)ws;  ws += (size_t)E_SZ*H_SZ*D_SZ*2;     //  4.2 MB
  float* gates = (float*)ws;  ws += (size_t)B_SZ*E_SZ*4;          //  0.26 MB
  short* h2gf  = (short*)ws;  ws += (size_t)B_SZ*E_SZ*H_SZ*2;     // 16.8 MB

  k_cvt_gate<<<dim3(4672), dim3(256), 0, stream>>>(x, W1, W2, W3, gw, gb,
                                                   xf, w1f, w2f, w3f, gates);
  k_gemm12f <<<dim3(1024), dim3(256), 0, stream>>>(xf, w1f, w2f, b1, b2, gates, h2gf);
  k_gemm3   <<<dim3(1024), dim3(256), 0, stream>>>(h2gf, w3f, b3, gates, out);
}

// Round 14
// 132.615 us; speedup vs baseline: 1.0936x; 1.0674x over previous
//
#include <hip/hip_runtime.h>

// ---------------------------------------------------------------------------
// MoE with adaptive gate, B=8192 D=2048 E=8 H=128, fp32 in/out, bf16 MFMA core
// k_cvt_gate : gate softmax + x LDS-transpose convert + W converts (round 11)
// k_gemm12f  : fused GEMM1+silu+GEMM2+silu+gate; BK=64 double-buffered core
//              (64 KB LDS, 512 blocks = 2/CU grid-capped, so LDS is free)
// k_gemm3    : out = h2g @ W3flat + gates @ b3 (m97-shape core, 1024 blocks)
// ---------------------------------------------------------------------------

typedef __attribute__((ext_vector_type(8))) short short8;   // 8 bf16 (4 VGPRs)
typedef __attribute__((ext_vector_type(4))) short bf16x4;   // 4 bf16
typedef __attribute__((ext_vector_type(4))) float f32x4;    // MFMA C/D

#define B_SZ 8192
#define D_SZ 2048
#define E_SZ 8
#define H_SZ 128

__device__ __forceinline__ short f2bf(float f) {
  unsigned u = __builtin_bit_cast(unsigned, f);
  unsigned r = (u + 0x7fffu + ((u >> 16) & 1u)) >> 16;   // RNE
  return (short)r;
}

__device__ __forceinline__ float silu_f(float v) {
  return v / (1.f + __expf(-v));
}

__device__ __forceinline__ void gload_lds16(const void* g, void* l) {
  __builtin_amdgcn_global_load_lds(
      (const __attribute__((address_space(1))) void*)g,
      (__attribute__((address_space(3))) void*)l,
      16, 0, 0);
}

// ---------------------------------------------------------------------------
// 128x128 core, BK=32, double-buffered 32 KB LDS.  256 thr, 4 waves (2x2),
// wave-out 64x64, acc[4][4].  (used by k_gemm3: 1024 blocks -> 4/CU)
// ---------------------------------------------------------------------------
template<int NHT>
__device__ __forceinline__ void core128(const short* __restrict__ A,
                                        const short* __restrict__ B,
                                        short* lds, f32x4 acc[4][4])
{
  const int tid  = threadIdx.x;
  const int lane = tid & 63;
  const int wid  = tid >> 6;
  const int wr = wid >> 1, wc = wid & 1;
  const int lm = lane & 15, lk = lane >> 4;
  const int wl = (tid & ~63) * 8;   // wave-uniform LDS offset (shorts)

  auto STAGE = [&](int eta) {       // 4 x global_load_lds(16B) per thread
    const size_t go = (size_t)(eta >> 1)*8192 + (size_t)(eta & 1)*4096;
    short* l = lds + (eta & 1)*8192;
    gload_lds16(A + go + tid*8,        l + wl);
    gload_lds16(A + go + 2048 + tid*8, l + 2048 + wl);
    gload_lds16(B + go + tid*8,        l + 4096 + wl);
    gload_lds16(B + go + 2048 + tid*8, l + 6144 + wl);
  };

  STAGE(0);
  __syncthreads();
  for (int eta = 0; eta < NHT; ++eta) {
    if (eta + 1 < NHT) STAGE(eta + 1);        // prefetch into other buffer
    const short* la = lds + (eta & 1)*8192 + lk*1024 + (wr*64 + lm)*8;
    const short* lb = lds + (eta & 1)*8192 + 4096 + lk*1024 + (wc*64 + lm)*8;
    short8 av[4], bv[4];
    #pragma unroll
    for (int f = 0; f < 4; ++f) av[f] = *(const short8*)(la + f*128);
    #pragma unroll
    for (int f = 0; f < 4; ++f) bv[f] = *(const short8*)(lb + f*128);
    #pragma unroll
    for (int i = 0; i < 4; ++i)
      #pragma unroll
      for (int j = 0; j < 4; ++j)
        acc[i][j] = __builtin_amdgcn_mfma_f32_16x16x32_bf16(av[i], bv[j], acc[i][j], 0, 0, 0);
    __syncthreads();   // prefetch drained; current-buffer reads complete
  }
}

// ---------------------------------------------------------------------------
// 128x128 core, BK=64 full-tile double-buffer, 64 KB LDS.  256 thr, 4 waves,
// wave-out 64x64, acc[4][4].  32 MFMA + 16 ds_reads per barrier pair (round-1
// proven: MfmaUtil 25.5%).  A/B buffers: A @ {0,8192}, B @ {16384,24576}.
// ---------------------------------------------------------------------------
template<int NKT>
__device__ __forceinline__ void core64k(const short* __restrict__ A,
                                        const short* __restrict__ B,
                                        short* lds, f32x4 acc[4][4])
{
  const int tid  = threadIdx.x;
  const int lane = tid & 63;
  const int wid  = tid >> 6;
  const int wr = wid >> 1, wc = wid & 1;
  const int lm = lane & 15, lk = lane >> 4;
  const int wbase = tid & ~63;

  auto STAGE = [&](int kt) {        // 8 x global_load_lds(16B) per thread
    const short* ga = A + (size_t)kt*8192;
    const short* gb = B + (size_t)kt*8192;
    short* la = lds + (kt & 1)*8192;
    short* lb = lds + 16384 + (kt & 1)*8192;
    #pragma unroll
    for (int q = 0; q < 4; ++q) {
      gload_lds16(ga + (q*256 + tid)*8, la + (q*256 + wbase)*8);
      gload_lds16(gb + (q*256 + tid)*8, lb + (q*256 + wbase)*8);
    }
  };

  STAGE(0);
  __syncthreads();
  for (int kt = 0; kt < NKT; ++kt) {
    if (kt + 1 < NKT) STAGE(kt + 1);
    const short* Ac = lds + (kt & 1)*8192;
    const short* Bc = lds + 16384 + (kt & 1)*8192;
    #pragma unroll
    for (int ks = 0; ks < 2; ++ks) {
      short8 av[4], bv[4];
      #pragma unroll
      for (int f = 0; f < 4; ++f)
        av[f] = *(const short8*)(Ac + (ks*4 + lk)*1024 + (wr*64 + f*16 + lm)*8);
      #pragma unroll
      for (int f = 0; f < 4; ++f)
        bv[f] = *(const short8*)(Bc + (ks*4 + lk)*1024 + (wc*64 + f*16 + lm)*8);
      #pragma unroll
      for (int i = 0; i < 4; ++i)
        #pragma unroll
        for (int j = 0; j < 4; ++j)
          acc[i][j] = __builtin_amdgcn_mfma_f32_16x16x32_bf16(av[i], bv[j], acc[i][j], 0, 0, 0);
    }
    __syncthreads();
  }
}

// ---------------------------------------------------------------------------
// K0: blocks [0,512)     : gate softmax, 16 rows/block (4 rows/wave, fp32)
//     blocks [512,2560)  : xf convert via LDS transpose (coalesced both sides)
//     blocks [2560,4672) : W1/W2/W3 converts (already coalesced)
// ---------------------------------------------------------------------------
__global__ __launch_bounds__(256)
void k_cvt_gate(const float* __restrict__ x,  const float* __restrict__ W1,
                const float* __restrict__ W2, const float* __restrict__ W3,
                const float* __restrict__ gw, const float* __restrict__ gb,
                short* __restrict__ xf, short* __restrict__ w1f,
                short* __restrict__ w2f, short* __restrict__ w3f,
                float* __restrict__ gates)
{
  __shared__ short lt[8192];   // 16 KB (xf branch only)
  const int b = blockIdx.x;
  const int tid = threadIdx.x;

  if (b < 512) {
    // ---- gate: wave handles 4 rows; gw fragments reg-cached, reused ----
    const int lane = tid & 63, wid = tid >> 6;
    const int row0 = b*16 + wid*4;
    float acc[4][8] = {};
    #pragma unroll
    for (int it = 0; it < 8; ++it) {
      const int k = it*256 + lane*4;
      float4 xv[4];
      #pragma unroll
      for (int r = 0; r < 4; ++r)
        xv[r] = *(const float4*)(x + (size_t)(row0 + r)*2048 + k);
      float4 gv[4][2];
      #pragma unroll
      for (int d = 0; d < 4; ++d) {
        gv[d][0] = *(const float4*)(gw + (size_t)(k + d)*8);
        gv[d][1] = *(const float4*)(gw + (size_t)(k + d)*8 + 4);
      }
      #pragma unroll
      for (int r = 0; r < 4; ++r) {
        const float xr[4] = {xv[r].x, xv[r].y, xv[r].z, xv[r].w};
        #pragma unroll
        for (int d = 0; d < 4; ++d) {
          acc[r][0] += xr[d]*gv[d][0].x; acc[r][1] += xr[d]*gv[d][0].y;
          acc[r][2] += xr[d]*gv[d][0].z; acc[r][3] += xr[d]*gv[d][0].w;
          acc[r][4] += xr[d]*gv[d][1].x; acc[r][5] += xr[d]*gv[d][1].y;
          acc[r][6] += xr[d]*gv[d][1].z; acc[r][7] += xr[d]*gv[d][1].w;
        }
      }
    }
    #pragma unroll
    for (int r = 0; r < 4; ++r)
      #pragma unroll
      for (int e = 0; e < 8; ++e)
        #pragma unroll
        for (int d = 1; d < 64; d <<= 1)
          acc[r][e] += __shfl_xor(acc[r][e], d, 64);
    if (lane < 4) {                      // lane r finalizes row0+r
      float lg[8], mx = -1e30f;
      #pragma unroll
      for (int e = 0; e < 8; ++e) { lg[e] = acc[lane][e] + gb[e]; mx = fmaxf(mx, lg[e]); }
      float s = 0.f;
      #pragma unroll
      for (int e = 0; e < 8; ++e) { lg[e] = __expf(lg[e] - mx); s += lg[e]; }
      const float inv = 1.f / s;
      #pragma unroll
      for (int e = 0; e < 8; ++e) gates[(size_t)(row0 + lane)*8 + e] = lg[e] * inv;
    }
  } else if (b < 2560) {
    // ---- xf: tile (bt,kt) = 128 rows x 64 k; coalesced read -> LDS frag ----
    const int t = b - 512;               // tile id (matches xf layout)
    const int bt = t >> 5, kt = t & 31;
    const float* xb = x + (size_t)bt*128*2048 + kt*64;
    #pragma unroll
    for (int u = 0; u < 8; ++u) {
      const int flat = u*1024 + tid*4;   // 0..8191, step 4
      const int row = flat >> 6, kk = flat & 63;
      const float4 v = *(const float4*)(xb + (size_t)row*2048 + kk);
      const int kg = kk >> 3;
      bf16x4 o;
      o[0] = f2bf(v.x); o[1] = f2bf(v.y); o[2] = f2bf(v.z); o[3] = f2bf(v.w);
      // frag idx q = kg*1024 + row*8 + (kk&7); physical = q ^ ((kg&7)<<3)
      const int s = (kg*1024 + row*8 + (kk & 7)) ^ ((kg & 7) << 3);
      *(bf16x4*)(lt + s) = o;
    }
    __syncthreads();
    short* dst = xf + (size_t)t*8192;
    #pragma unroll
    for (int u = 0; u < 4; ++u) {
      const int li = u*2048 + tid*8;
      const int kg = li >> 10;
      const int s = li ^ ((kg & 7) << 3);
      *(short8*)(dst + li) = *(const short8*)(lt + s);
    }
  } else {
    // ---- W converts (coalesced per-j 256B runs) ----
    const int gi = (b - 2560)*256 + tid + 2097152;
    if (gi < 2097152 + 262144) {              // w1f: [e8][kt32] tiles of W1[e]
      const int g = gi - 2097152;
      const int t = g >> 10, r = g & 1023;
      const int e = t >> 5, kt = t & 31;
      const int kg = r >> 7, p = r & 127;
      const int k0 = kt*64 + kg*8;
      short8 o;
      #pragma unroll
      for (int j = 0; j < 8; ++j)
        o[j] = f2bf(W1[(size_t)e*262144 + (size_t)(k0 + j)*128 + p]);
      *(short8*)(w1f + (size_t)g*8) = o;
    } else if (gi < 2097152 + 262144 + 16384) { // w2f: [e8][kt2] tiles of W2[e]
      const int g = gi - (2097152 + 262144);
      const int t = g >> 10, r = g & 1023;
      const int e = t >> 1, kt = t & 1;
      const int kg = r >> 7, p = r & 127;
      const int k0 = kt*64 + kg*8;
      short8 o;
      #pragma unroll
      for (int j = 0; j < 8; ++j)
        o[j] = f2bf(W2[(size_t)e*16384 + (size_t)(k0 + j)*128 + p]);
      *(short8*)(w2f + (size_t)g*8) = o;
    } else if (gi < 2637824) {                // w3f: [nt16][kt16] tiles of W3flat
      const int g = gi - 2375680;
      const int t = g >> 10, r = g & 1023;
      const int nt = t >> 4, kt = t & 15;
      const int kg = r >> 7, p = r & 127;
      const int k0 = kt*64 + kg*8;
      short8 o;
      #pragma unroll
      for (int j = 0; j < 8; ++j) {
        const int k = k0 + j;                 // k = e*128 + h
        o[j] = f2bf(W3[(size_t)(k >> 7)*262144 + (size_t)(k & 127)*2048 + nt*128 + p]);
      }
      *(short8*)(w3f + (size_t)g*8) = o;
    }
  }
}

// ---------------------------------------------------------------------------
// K2: fused GEMM1+silu+GEMM2+silu+gate -> h2gf frag tiles.  128x128, BK=64.
// grid 512 XCD-chunked: bt = xcd*8+(idx&7) (0..63), e = idx>>3 (0..7).
// Core: 64 KB LDS double-buffer (grid-capped at 2 blocks/CU, so LDS is free).
// Epilogue: h1 -> first 32 KB of LDS; W2 direct global->VGPR; GEMM2; dump.
// ---------------------------------------------------------------------------
__global__ __launch_bounds__(256, 2)
void k_gemm12f(const short* __restrict__ xf, const short* __restrict__ w1f,
               const short* __restrict__ w2f,
               const float* __restrict__ b1, const float* __restrict__ b2,
               const float* __restrict__ gates, short* __restrict__ h2gf)
{
  __shared__ short lds[32768];   // 64 KB
  const int b = blockIdx.x;
  const int xcd = b & 7, idx = b >> 3;   // idx 0..63
  const int bt = xcd*8 + (idx & 7);      // 0..63
  const int e  = idx >> 3;               // 0..7

  f32x4 acc[4][4] = {};
  core64k<32>(xf  + (size_t)bt*32*8192,
              w1f + (size_t)e*32*8192,
              lds, acc);
  // core's final __syncthreads: LDS free for epilogue

  const int tid = threadIdx.x, lane = tid & 63, wid = tid >> 6;
  const int wr = wid >> 1, wc = wid & 1;
  const int lm = lane & 15, lk = lane >> 4, lr = lane >> 4;

  // ---- W2 fragments direct global->VGPR (L2-resident) ----
  short8 bvAll[2][2][4];
  #pragma unroll
  for (int kt = 0; kt < 2; ++kt)
  #pragma unroll
  for (int ks = 0; ks < 2; ++ks)
  #pragma unroll
  for (int fn = 0; fn < 4; ++fn)
    bvAll[kt][ks][fn] = *(const short8*)(
        w2f + (size_t)e*16384 + kt*8192 + (ks*4 + lk)*1024
            + (wc*64 + fn*16 + lm)*8);

  // ---- gates for my 16 output rows ----
  float gv[4][4];
  #pragma unroll
  for (int fm = 0; fm < 4; ++fm)
  #pragma unroll
  for (int i = 0; i < 4; ++i)
    gv[fm][i] = gates[(size_t)(bt*128 + wr*64 + fm*16 + lr*4 + i)*8 + e];

  // ---- h1 = silu(acc + b1) -> LDS frag [kg16][p128][j8] (32 KB) ----
  float b1v[4];
  #pragma unroll
  for (int fn = 0; fn < 4; ++fn) b1v[fn] = b1[e*H_SZ + wc*64 + fn*16 + lm];
  #pragma unroll
  for (int fm = 0; fm < 4; ++fm)
  #pragma unroll
  for (int i = 0; i < 4; ++i) {
    const int m = wr*64 + fm*16 + lr*4 + i;
    #pragma unroll
    for (int fn = 0; fn < 4; ++fn) {
      const int n = wc*64 + fn*16 + lm;          // h index 0..127
      const float v = silu_f(acc[fm][fn][i] + b1v[fn]);
      lds[(n >> 3)*1024 + m*8 + (n & 7)] = f2bf(v);
    }
  }
  __syncthreads();

  // ---- GEMM2: h2 = h1 @ W2[e], K=128 ----
  f32x4 acc2[4][4] = {};
  #pragma unroll
  for (int kt = 0; kt < 2; ++kt)
  #pragma unroll
  for (int ks = 0; ks < 2; ++ks) {
    short8 av[4];
    #pragma unroll
    for (int f = 0; f < 4; ++f)
      av[f] = *(const short8*)(lds + (kt*8 + ks*4 + lk)*1024 + (wr*64 + f*16 + lm)*8);
    #pragma unroll
    for (int i = 0; i < 4; ++i)
      #pragma unroll
      for (int j = 0; j < 4; ++j)
        acc2[i][j] = __builtin_amdgcn_mfma_f32_16x16x32_bf16(
            av[i], bvAll[kt][ks][j], acc2[i][j], 0, 0, 0);
  }
  __syncthreads();   // all h1 reads done; reuse LDS for h2

  // ---- h2 = silu(acc2 + b2) * gate -> LDS frag ----
  float b2v[4];
  #pragma unroll
  for (int fn = 0; fn < 4; ++fn) b2v[fn] = b2[e*H_SZ + wc*64 + fn*16 + lm];
  #pragma unroll
  for (int fm = 0; fm < 4; ++fm)
  #pragma unroll
  for (int i = 0; i < 4; ++i) {
    const int m = wr*64 + fm*16 + lr*4 + i;
    const float g = gv[fm][i];
    #pragma unroll
    for (int fn = 0; fn < 4; ++fn) {
      const int n = wc*64 + fn*16 + lm;
      const float v = silu_f(acc2[fm][fn][i] + b2v[fn]) * g;
      lds[(n >> 3)*1024 + m*8 + (n & 7)] = f2bf(v);
    }
  }
  __syncthreads();

  // ---- dump h2 frag tiles (bt*16 + e*2 + t2), coalesced short8 ----
  #pragma unroll
  for (int q = 0; q < 8; ++q) {
    const int li = q*2048 + tid*8;               // 0..16383
    const int t2 = li >> 13, off = li & 8191;
    *(short8*)(h2gf + ((size_t)bt*16 + e*2 + t2)*8192 + off) =
        *(const short8*)(lds + li);
  }
}

// ---------------------------------------------------------------------------
// K4: out = h2g @ W3flat + gates @ b3.  1024 blocks XCD-chunked.
// ---------------------------------------------------------------------------
__global__ __launch_bounds__(256, 4)
void k_gemm3(const short* __restrict__ h2gf, const short* __restrict__ w3f,
             const float* __restrict__ b3, const float* __restrict__ gates,
             float* __restrict__ out)
{
  __shared__ short lds[16384];   // 32 KB
  const int b = blockIdx.x;
  const int xcd = b & 7, idx = b >> 3;   // idx 0..127
  const int bt = xcd*8 + (idx & 7);      // 0..63
  const int nt = idx >> 3;               // 0..15

  f32x4 acc[4][4] = {};
  core128<32>(h2gf + (size_t)bt*16*8192,
              w3f  + (size_t)nt*16*8192,
              lds, acc);

  const int tid = threadIdx.x, lane = tid & 63, wid = tid >> 6;
  const int wr = wid >> 1, wc = wid & 1, lm = lane & 15, lr = lane >> 4;
  float b3c[4][8];
  #pragma unroll
  for (int fn = 0; fn < 4; ++fn) {
    const int n = nt*128 + wc*64 + fn*16 + lm;
    #pragma unroll
    for (int e = 0; e < 8; ++e) b3c[fn][e] = b3[(size_t)e*D_SZ + n];
  }
  #pragma unroll
  for (int fm = 0; fm < 4; ++fm)
  #pragma unroll
  for (int i = 0; i < 4; ++i) {
    const int m = bt*128 + wr*64 + fm*16 + lr*4 + i;
    const float4 ga  = *(const float4*)(gates + (size_t)m*8);
    const float4 gbv = *(const float4*)(gates + (size_t)m*8 + 4);
    #pragma unroll
    for (int fn = 0; fn < 4; ++fn) {
      const int n = nt*128 + wc*64 + fn*16 + lm;
      const float bias = ga.x*b3c[fn][0] + ga.y*b3c[fn][1] + ga.z*b3c[fn][2] + ga.w*b3c[fn][3]
                       + gbv.x*b3c[fn][4] + gbv.y*b3c[fn][5] + gbv.z*b3c[fn][6] + gbv.w*b3c[fn][7];
      out[(size_t)m*D_SZ + n] = acc[fm][fn][i] + bias;
    }
  }
}

// ---------------------------------------------------------------------------
extern "C" void kernel_launch(void* const* d_in, const int* in_sizes, int n_in,
                              void* d_out, int out_size, void* d_ws, size_t ws_size,
                              hipStream_t stream)
{
  (void)in_sizes; (void)n_in; (void)out_size; (void)ws_size;
  const float* x  = (const float*)d_in[0];
  const float* gw = (const float*)d_in[1];
  const float* gb = (const float*)d_in[2];
  const float* W1 = (const float*)d_in[3];
  const float* b1 = (const float*)d_in[4];
  const float* W2 = (const float*)d_in[5];
  const float* b2 = (const float*)d_in[6];
  const float* W3 = (const float*)d_in[7];
  const float* b3 = (const float*)d_in[8];
  float* out = (float*)d_out;

  char* ws = (char*)d_ws;
  short* xf    = (short*)ws;  ws += (size_t)B_SZ*D_SZ*2;          // 33.5 MB
  short* w1f   = (short*)ws;  ws += (size_t)E_SZ*D_SZ*H_SZ*2;     //  4.2 MB
  short* w2f   = (short*)ws;  ws += (size_t)E_SZ*H_SZ*H_SZ*2;     //  0.26 MB
  short* w3f   = (short*)ws;  ws += (size_t)E_SZ*H_SZ*D_SZ*2;     //  4.2 MB
  float* gates = (float*)ws;  ws += (size_t)B_SZ*E_SZ*4;          //  0.26 MB
  short* h2gf  = (short*)ws;  ws += (size_t)B_SZ*E_SZ*H_SZ*2;     // 16.8 MB

  k_cvt_gate<<<dim3(4672), dim3(256), 0, stream>>>(x, W1, W2, W3, gw, gb,
                                                   xf, w1f, w2f, w3f, gates);
  k_gemm12f <<<dim3(512),  dim3(256), 0, stream>>>(xf, w1f, w2f, b1, b2, gates, h2gf);
  k_gemm3   <<<dim3(1024), dim3(256), 0, stream>>>(h2gf, w3f, b3, gates, out);
}